// Round 1
// baseline (140.894 us; speedup 1.0000x reference)
//
#include <hip/hip_runtime.h>
#include <math.h>

#define NQ 14
#define DIM (1 << NQ)        // 16384 amplitudes
#define NPAIR (DIM / 2)      // 8192
#define NCPAIR (DIM / 4)     // 4096 (controlled-gate pairs)
#define NP 140               // params per batch element
#define NTHREADS 1024
#define NWAVES (NTHREADS / 64)

struct c32 { float re, im; };

__device__ __forceinline__ c32 cmul(c32 a, c32 b) {
    return { a.re * b.re - a.im * b.im, a.re * b.im + a.im * b.re };
}

// controlled-RX on (ctrl, tgt) qubits; psi in LDS
__device__ __forceinline__ void apply_crx(float2* psi, float th, int ctrl, int tgt, int tid) {
    float sh, ch;
    __sincosf(0.5f * th, &sh, &ch);
    const int bc = NQ - 1 - ctrl;
    const int bt = NQ - 1 - tgt;
    const int blo = bc < bt ? bc : bt;
    const int bhi = bc < bt ? bt : bc;
    const int mlo = (1 << blo) - 1;
    const int mhi = (1 << bhi) - 1;
    for (int p = tid; p < NCPAIR; p += NTHREADS) {
        int t0 = ((p >> blo) << (blo + 1)) | (p & mlo);
        int t1 = ((t0 >> bhi) << (bhi + 1)) | (t0 & mhi);
        int i0 = t1 | (1 << bc);       // ctrl=1, tgt=0
        int i1 = i0 | (1 << bt);       // ctrl=1, tgt=1
        float2 A0 = psi[i0], A1 = psi[i1];
        // RX: n0 = c*a0 - i*s*a1 ; n1 = -i*s*a0 + c*a1
        float2 n0 = make_float2(ch * A0.x + sh * A1.y, ch * A0.y - sh * A1.x);
        float2 n1 = make_float2(ch * A1.x + sh * A0.y, ch * A1.y - sh * A0.x);
        psi[i0] = n0;
        psi[i1] = n1;
    }
}

__global__ __launch_bounds__(NTHREADS)
void qfe_kernel(const float* __restrict__ params,
                const float* __restrict__ base,
                float* __restrict__ out)
{
    __shared__ float2 psi[DIM];          // 128 KB
    __shared__ float ang[NP];
    __shared__ float red[NWAVES][4];

    const int b = blockIdx.x;
    const int tid = threadIdx.x;

    // angles = sigmoid(params + base) * 2pi
    for (int i = tid; i < NP; i += NTHREADS) {
        float x = params[b * NP + i] + base[i];
        float s = 1.0f / (1.0f + __expf(-x));
        ang[i] = s * 6.28318530717958647692f;
    }
    // init |0...0>
    for (int i = tid; i < DIM; i += NTHREADS) {
        psi[i] = (i == 0) ? make_float2(1.f, 0.f) : make_float2(0.f, 0.f);
    }
    __syncthreads();

    int idx = 0;
    for (int layer = 0; layer < 2; ++layer) {
        // --- fused RX*RY*RZ on each qubit ---
        for (int q = 0; q < NQ; ++q) {
            float t1 = ang[idx], t2 = ang[idx + 1], t3 = ang[idx + 2];
            idx += 3;
            float s1, c1, s2, c2, s3, c3;
            __sincosf(0.5f * t1, &s1, &c1);
            __sincosf(0.5f * t2, &s2, &c2);
            __sincosf(0.5f * t3, &s3, &c3);
            // M = Ry@Rx
            c32 m00 = { c2 * c1,  s2 * s1 };
            c32 m01 = { -s2 * c1, -c2 * s1 };
            c32 m10 = { s2 * c1,  -c2 * s1 };
            c32 m11 = { c2 * c1,  -s2 * s1 };
            // U = Rz @ M : row0 *= e^{-i t3/2}, row1 *= e^{+i t3/2}
            c32 em = { c3, -s3 }, ep = { c3, s3 };
            c32 u00 = cmul(em, m00), u01 = cmul(em, m01);
            c32 u10 = cmul(ep, m10), u11 = cmul(ep, m11);

            const int bb = NQ - 1 - q;
            const int mask = 1 << bb;
            for (int p = tid; p < NPAIR; p += NTHREADS) {
                int i0 = ((p >> bb) << (bb + 1)) | (p & (mask - 1));
                int i1 = i0 | mask;
                float2 A0 = psi[i0], A1 = psi[i1];
                c32 a0 = { A0.x, A0.y }, a1 = { A1.x, A1.y };
                c32 p00 = cmul(u00, a0), p01 = cmul(u01, a1);
                c32 p10 = cmul(u10, a0), p11 = cmul(u11, a1);
                psi[i0] = make_float2(p00.re + p01.re, p00.im + p01.im);
                psi[i1] = make_float2(p10.re + p11.re, p10.im + p11.im);
            }
            __syncthreads();
        }
        // --- forward CRX ring ---
        for (int i = 0; i < NQ; ++i) {
            apply_crx(psi, ang[idx++], i, (i + 1) % NQ, tid);
            __syncthreads();
        }
        // --- backward CRX ring ---
        for (int i = NQ - 1; i >= 0; --i) {
            apply_crx(psi, ang[idx++], i, (i + NQ - 1) % NQ, tid);
            __syncthreads();
        }
    }

    // --- measurements: X, Y, Z per wire ---
    for (int w = 0; w < NQ; ++w) {
        const int bb = NQ - 1 - w;
        const int mask = 1 << bb;
        float sx = 0.f, sy = 0.f, sz = 0.f;
        for (int p = tid; p < NPAIR; p += NTHREADS) {
            int i0 = ((p >> bb) << (bb + 1)) | (p & (mask - 1));
            int i1 = i0 | mask;
            float2 A0 = psi[i0], A1 = psi[i1];
            // conj(a0)*a1
            sx += A0.x * A1.x + A0.y * A1.y;
            sy += A0.x * A1.y - A0.y * A1.x;
            sz += (A0.x * A0.x + A0.y * A0.y) - (A1.x * A1.x + A1.y * A1.y);
        }
        for (int off = 32; off > 0; off >>= 1) {
            sx += __shfl_down(sx, off);
            sy += __shfl_down(sy, off);
            sz += __shfl_down(sz, off);
        }
        const int wave = tid >> 6;
        if ((tid & 63) == 0) {
            red[wave][0] = sx; red[wave][1] = sy; red[wave][2] = sz;
        }
        __syncthreads();
        if (tid == 0) {
            float X = 0.f, Y = 0.f, Z = 0.f;
            for (int k = 0; k < NWAVES; ++k) {
                X += red[k][0]; Y += red[k][1]; Z += red[k][2];
            }
            out[b * 3 * NQ + w]          = 2.f * X;
            out[b * 3 * NQ + NQ + w]     = 2.f * Y;
            out[b * 3 * NQ + 2 * NQ + w] = Z;
        }
        __syncthreads();
    }
}

extern "C" void kernel_launch(void* const* d_in, const int* in_sizes, int n_in,
                              void* d_out, int out_size, void* d_ws, size_t ws_size,
                              hipStream_t stream) {
    const float* params = (const float*)d_in[0];   // [B, 140]
    const float* base   = (const float*)d_in[1];   // [140]
    float* out = (float*)d_out;                    // [B, 42]
    const int B = in_sizes[0] / NP;
    qfe_kernel<<<B, NTHREADS, 0, stream>>>(params, base, out);
}